// Round 7
// baseline (197.901 us; speedup 1.0000x reference)
//
#include <hip/hip_runtime.h>
#include <hip/hip_bf16.h>

typedef __bf16 bf16_t;
typedef __bf16 bf16x8 __attribute__((ext_vector_type(8)));
typedef __bf16 bf16x4 __attribute__((ext_vector_type(4)));
typedef float f32x4 __attribute__((ext_vector_type(4)));

constexpr int LD = 3072;

#define MFMA_16x16x32(a, b, c) __builtin_amdgcn_mfma_f32_16x16x32_bf16((a), (b), (c), 0, 0, 0)

#define GLOAD_LDS16(g, l)                                               \
  __builtin_amdgcn_global_load_lds(                                     \
      (const __attribute__((address_space(1))) void*)(g),               \
      (__attribute__((address_space(3))) void*)(l), 16, 0, 0)

#define TRREAD(dst, addr, imm) \
  asm volatile("ds_read_b64_tr_b16 %0, %1 offset:" imm : "=v"(dst) : "v"(addr))

// ---------------- fp32 -> bf16 convert (16B-store vectorized) ----------------
__global__ void cvt_kernel(const float* __restrict__ in, bf16_t* __restrict__ out, int n8) {
  int i = blockIdx.x * blockDim.x + threadIdx.x;
  if (i >= n8) return;
  const float4 a = reinterpret_cast<const float4*>(in)[2 * i];
  const float4 c = reinterpret_cast<const float4*>(in)[2 * i + 1];
  bf16x8 o;
  o[0] = (bf16_t)a.x; o[1] = (bf16_t)a.y; o[2] = (bf16_t)a.z; o[3] = (bf16_t)a.w;
  o[4] = (bf16_t)c.x; o[5] = (bf16_t)c.y; o[6] = (bf16_t)c.z; o[7] = (bf16_t)c.w;
  reinterpret_cast<bf16x8*>(out)[i] = o;
}

// ------------- transpose + convert: out[c][r] = (bf16) in[r][c] -------------
__global__ void tcvt_kernel(const float* __restrict__ in, bf16_t* __restrict__ out, int R, int C) {
  __shared__ float tile[32][33];
  const int c0 = blockIdx.x * 32, r0 = blockIdx.y * 32;
  const int tx = threadIdx.x & 31, ty = threadIdx.x >> 5;  // 32 x 8
#pragma unroll
  for (int i = 0; i < 32; i += 8)
    tile[ty + i][tx] = in[(size_t)(r0 + ty + i) * C + (c0 + tx)];
  __syncthreads();
#pragma unroll
  for (int i = 0; i < 32; i += 8)
    out[(size_t)(c0 + ty + i) * R + (r0 + tx)] = (bf16_t)tile[tx][ty + i];
}

// ------------- bf16 GEMM: C[M][N] = A[M][K] * Bt[N][K]^T -------------
template <typename OutT>
__global__ __launch_bounds__(256) void gemm_bt_kernel(
    const bf16_t* __restrict__ A, const bf16_t* __restrict__ Bt, OutT* __restrict__ C,
    int M, int N, int K, int q_cols, float q_scale) {
  __shared__ bf16_t As[2][4096];
  __shared__ bf16_t Bs[2][4096];
  const int tid = threadIdx.x;
  const int lane = tid & 63;
  const int wave = tid >> 6;
  const int l15 = lane & 15, lg = lane >> 4;
  const int wr = wave >> 1, wc = wave & 1;
  const int brow = blockIdx.y * 128, bcol = blockIdx.x * 128;

  f32x4 acc[4][4] = {};

  const int srow = tid >> 2;
  const int scol = (tid & 3) * 8;
  const bf16_t* Ag = A + (size_t)(brow + srow) * K + scol;
  const bf16_t* Bg = Bt + (size_t)(bcol + srow) * K + scol;

  {
    bf16_t* aw = &As[0][wave * 512];
    bf16_t* bw = &Bs[0][wave * 512];
    GLOAD_LDS16(Ag, aw);
    GLOAD_LDS16(Ag + (size_t)64 * K, aw + 2048);
    GLOAD_LDS16(Bg, bw);
    GLOAD_LDS16(Bg + (size_t)64 * K, bw + 2048);
  }
  __syncthreads();

  const int nsteps = K >> 5;
  for (int i = 0; i < nsteps; i++) {
    if (i + 1 < nsteps) {
      const int k0 = (i + 1) << 5;
      bf16_t* aw = &As[(i + 1) & 1][wave * 512];
      bf16_t* bw = &Bs[(i + 1) & 1][wave * 512];
      GLOAD_LDS16(Ag + k0, aw);
      GLOAD_LDS16(Ag + k0 + (size_t)64 * K, aw + 2048);
      GLOAD_LDS16(Bg + k0, bw);
      GLOAD_LDS16(Bg + k0 + (size_t)64 * K, bw + 2048);
    }
    const bf16_t* as = As[i & 1];
    const bf16_t* bs = Bs[i & 1];
    bf16x8 af[4], bfr[4];
#pragma unroll
    for (int j = 0; j < 4; j++)
      af[j] = *reinterpret_cast<const bf16x8*>(as + (wr * 64 + j * 16 + l15) * 32 + lg * 8);
#pragma unroll
    for (int j = 0; j < 4; j++)
      bfr[j] = *reinterpret_cast<const bf16x8*>(bs + (wc * 64 + j * 16 + l15) * 32 + lg * 8);
#pragma unroll
    for (int j = 0; j < 4; j++)
#pragma unroll
      for (int k = 0; k < 4; k++)
        acc[j][k] = MFMA_16x16x32(af[j], bfr[k], acc[j][k]);
    __syncthreads();
  }

  const float sc = (bcol < q_cols) ? q_scale : 1.0f;  // block-uniform
#pragma unroll
  for (int i = 0; i < 4; i++)
#pragma unroll
    for (int j = 0; j < 4; j++)
#pragma unroll
      for (int r = 0; r < 4; r++) {
        const size_t row = (size_t)(brow + wr * 64 + i * 16 + lg * 4 + r);
        const size_t col = (size_t)(bcol + wc * 64 + j * 16 + l15);
        C[row * N + col] = (OutT)(acc[i][j][r] * sc);
      }
}

// ------------- fused attention (v7 = v6 with the pu overflow fixed) -------------
// Both K and V staged through LDS once per block (no per-wave K registers).
// K: [64][64] tile, 16B-chunk XOR swizzle (chunk c of row r stored at c^(r&7))
//    applied on the GLOBAL source (rule #21); read back with the same XOR.
// V: pi-subtiled layout for ds_read_b64_tr_b16 (unchanged from v4/v5).
// Loop (2-phase): stage(t+1) -> QK(ds_read K) -> trread V issue -> softmax
// (hides LDS latency) -> PV -> __syncthreads (implicit vmcnt(0) drains stage).
__device__ __forceinline__ unsigned pack_bf16_pair(float a, float b) {
  union { __hip_bfloat162 h; unsigned u; } c;
  c.h = __float22bfloat162_rn(float2{a, b});  // v_cvt_pk_bf16_f32
  return c.u;
}

__global__ __launch_bounds__(256, 4) void attn_kernel(const bf16_t* __restrict__ qkv,
                                                      bf16_t* __restrict__ ctx) {
  __shared__ bf16_t Ks[2][4096];  // swizzled K, double-buffered (16 KB)
  __shared__ bf16_t Vs[2][4096];  // pi-subtiled V, double-buffered (16 KB)
  const int tid = threadIdx.x, lane = tid & 63, wave = tid >> 6;
  const int l15 = lane & 15, lg = (lane >> 4) & 3;
  // XCD-aware decode: all 8 q-tiles of one (h,b) on one XCD (K/V L2 reuse)
  const int flat = blockIdx.x;
  const int xcd = flat & 7, rr = flat >> 3;
  const int qt = rr & 7;
  const int hb = xcd * 16 + (rr >> 3);
  const int h = hb & 15, b = hb >> 4;
  const size_t base = (size_t)b * 1024 * LD;
  const int qbase = qt * 128 + wave * 32;

  bf16x8 qa[2][2];
#pragma unroll
  for (int s = 0; s < 2; s++) {
    const bf16_t* qp = qkv + base + (size_t)(qbase + s * 16 + l15) * LD + h * 64 + lg * 8;
    qa[s][0] = *reinterpret_cast<const bf16x8*>(qp);
    qa[s][1] = *reinterpret_cast<const bf16x8*>(qp + 32);
  }

  const bf16_t* Kb = qkv + base + 1024 + h * 64;
  const bf16_t* Vb = qkv + base + 2048 + h * 64;

  // --- K staging source (XOR-swizzled chunks). Chunk i = (w*2+j)*64 + lane:
  //     r = w*16 + j*8 + (lane>>3), cswz = lane&7, global col-chunk = cswz^(r&7)
  const int krr = lane >> 3;                 // == r&7 (w*16, j*8 are 0 mod 8)
  const int kcc = (lane & 7) ^ krr;
  const bf16_t* ksrc0 = Kb + (size_t)(wave * 16 + krr) * LD + kcc * 8;
  const bf16_t* ksrc1 = ksrc0 + (size_t)8 * LD;

  // --- V staging source (pi layout, unchanged) ---
  const int vd0 = (lane & 1) * 8 + wave * 16;
  const int vkv = ((lane >> 1) & 3) + ((lane >> 3) & 3) * 4 + (lane >> 5) * 16;
  const bf16_t* vsrc0 = Vb + (size_t)vkv * LD + vd0;  // kv>>5 == 0
  const bf16_t* vsrc1 = vsrc0 + (size_t)32 * LD;      // kv>>5 == 1

  bf16_t* ksb = &Ks[0][0];
  bf16_t* vsb = &Vs[0][0];
  const char* ksr = (const char*)&Ks[0][0];
  const unsigned vs_byte =
      (unsigned)(size_t)(__attribute__((address_space(3))) void*)(&Vs[0][0]);
  const unsigned tr_lane = vs_byte + lane * 8;

  // K fragment read offsets (bytes within buffer): row R = tt*16 + l15,
  // chunk C in {lg, 4+lg}; byte = R*128 + (C ^ (R&7))*16, R&7 == l15&7.
  const int rx7 = l15 & 7;
  const unsigned kb0 = (unsigned)(l15 * 128 + ((lg ^ rx7) << 4));
  const unsigned kb1 = (unsigned)(l15 * 128 + (((4 | lg) ^ rx7) << 4));

  float lr[2] = {0.f, 0.f};
  f32x4 oacc[2][4] = {};

  // prologue: stage tile 0 into buf 0
  GLOAD_LDS16(ksrc0, ksb + wave * 1024);
  GLOAD_LDS16(ksrc1, ksb + wave * 1024 + 512);
  GLOAD_LDS16(vsrc0, vsb + wave * 1024);
  GLOAD_LDS16(vsrc1, vsb + wave * 1024 + 512);
  ksrc0 += (size_t)64 * LD; ksrc1 += (size_t)64 * LD;
  vsrc0 += (size_t)64 * LD; vsrc1 += (size_t)64 * LD;
  __syncthreads();

  for (int t = 0; t < 16; t++) {
    const int cur = t & 1;
    if (t < 15) {  // stage next tile; drained by this iter's end-barrier
      bf16_t* kd = ksb + (cur ^ 1) * 4096 + wave * 1024;
      bf16_t* vd = vsb + (cur ^ 1) * 4096 + wave * 1024;
      GLOAD_LDS16(ksrc0, kd);
      GLOAD_LDS16(ksrc1, kd + 512);
      GLOAD_LDS16(vsrc0, vd);
      GLOAD_LDS16(vsrc1, vd + 512);
      ksrc0 += (size_t)64 * LD; ksrc1 += (size_t)64 * LD;
      vsrc0 += (size_t)64 * LD; vsrc1 += (size_t)64 * LD;
    }

    // ---- S^T = K Q^T : K fragments from swizzled LDS ----
    f32x4 sacc[2][4] = {};
    const char* kt = ksr + cur * 8192;
    __builtin_amdgcn_s_setprio(1);
#pragma unroll
    for (int tt = 0; tt < 4; tt++) {
      const bf16x8 k0 = *reinterpret_cast<const bf16x8*>(kt + tt * 2048 + kb0);
      const bf16x8 k1 = *reinterpret_cast<const bf16x8*>(kt + tt * 2048 + kb1);
      sacc[0][tt] = MFMA_16x16x32(k0, qa[0][0], sacc[0][tt]);
      sacc[0][tt] = MFMA_16x16x32(k1, qa[0][1], sacc[0][tt]);
      sacc[1][tt] = MFMA_16x16x32(k0, qa[1][0], sacc[1][tt]);
      sacc[1][tt] = MFMA_16x16x32(k1, qa[1][1], sacc[1][tt]);
    }
    __builtin_amdgcn_s_setprio(0);

    // ---- issue tr-reads now; latency hides under softmax ----
    const unsigned ta = tr_lane + (unsigned)cur * 8192;
    bf16x4 tl0, th0, tl1, th1, tl2, th2, tl3, th3, tl4, th4, tl5, th5, tl6, th6, tl7, th7;
    TRREAD(tl0, ta, "0");    TRREAD(th0, ta, "512");    // ks0 dt0
    TRREAD(tl1, ta, "1024"); TRREAD(th1, ta, "1536");   // ks1 dt0
    TRREAD(tl2, ta, "2048"); TRREAD(th2, ta, "2560");   // ks0 dt1
    TRREAD(tl3, ta, "3072"); TRREAD(th3, ta, "3584");   // ks1 dt1
    TRREAD(tl4, ta, "4096"); TRREAD(th4, ta, "4608");   // ks0 dt2
    TRREAD(tl5, ta, "5120"); TRREAD(th5, ta, "5632");   // ks1 dt2
    TRREAD(tl6, ta, "6144"); TRREAD(th6, ta, "6656");   // ks0 dt3
    TRREAD(tl7, ta, "7168"); TRREAD(th7, ta, "7680");   // ks1 dt3
    __builtin_amdgcn_sched_barrier(0);  // softmax stays below tr-read issue

    // ---- no-max softmax (scale pre-folded into Q at gemm1 epilogue) ----
    // P fragment: pa[s][ks] word w: (tt,j) -> index s*8 + (tt>>1)*4 + (tt&1)*2 + j
    unsigned pu[16];
    float ls0 = 0.f, ls1 = 0.f;
#pragma unroll
    for (int tt = 0; tt < 4; tt++) {
      const float a0 = __builtin_exp2f(sacc[0][tt][0]);
      const float a1 = __builtin_exp2f(sacc[0][tt][1]);
      const float a2 = __builtin_exp2f(sacc[0][tt][2]);
      const float a3 = __builtin_exp2f(sacc[0][tt][3]);
      ls0 += (a0 + a1) + (a2 + a3);
      pu[(tt >> 1) * 4 + (tt & 1) * 2 + 0] = pack_bf16_pair(a0, a1);
      pu[(tt >> 1) * 4 + (tt & 1) * 2 + 1] = pack_bf16_pair(a2, a3);
      const float b0 = __builtin_exp2f(sacc[1][tt][0]);
      const float b1 = __builtin_exp2f(sacc[1][tt][1]);
      const float b2 = __builtin_exp2f(sacc[1][tt][2]);
      const float b3 = __builtin_exp2f(sacc[1][tt][3]);
      ls1 += (b0 + b1) + (b2 + b3);
      pu[8 + (tt >> 1) * 4 + (tt & 1) * 2 + 0] = pack_bf16_pair(b0, b1);
      pu[8 + (tt >> 1) * 4 + (tt & 1) * 2 + 1] = pack_bf16_pair(b2, b3);
    }
    lr[0] += ls0;
    lr[1] += ls1;
    bf16x8 pa[2][2];
    pa[0][0] = *reinterpret_cast<bf16x8*>(&pu[0]);
    pa[0][1] = *reinterpret_cast<bf16x8*>(&pu[4]);
    pa[1][0] = *reinterpret_cast<bf16x8*>(&pu[8]);
    pa[1][1] = *reinterpret_cast<bf16x8*>(&pu[12]);

    asm volatile("s_waitcnt lgkmcnt(0)" ::: "memory");
    __builtin_amdgcn_sched_barrier(0);

    bf16x8 vb[2][4];
    vb[0][0] = __builtin_shufflevector(tl0, th0, 0, 1, 2, 3, 4, 5, 6, 7);
    vb[1][0] = __builtin_shufflevector(tl1, th1, 0, 1, 2, 3, 4, 5, 6, 7);
    vb[0][1] = __builtin_shufflevector(tl2, th2, 0, 1, 2, 3, 4, 5, 6, 7);
    vb[1][1] = __builtin_shufflevector(tl3, th3, 0, 1, 2, 3, 4, 5, 6, 7);
    vb[0][2] = __builtin_shufflevector(tl4, th4, 0, 1, 2, 3, 4, 5, 6, 7);
    vb[1][2] = __builtin_shufflevector(tl5, th5, 0, 1, 2, 3, 4, 5, 6, 7);
    vb[0][3] = __builtin_shufflevector(tl6, th6, 0, 1, 2, 3, 4, 5, 6, 7);
    vb[1][3] = __builtin_shufflevector(tl7, th7, 0, 1, 2, 3, 4, 5, 6, 7);

    __builtin_amdgcn_s_setprio(1);
#pragma unroll
    for (int s = 0; s < 2; s++)
#pragma unroll
      for (int dt = 0; dt < 4; dt++) {
        oacc[s][dt] = MFMA_16x16x32(pa[s][0], vb[0][dt], oacc[s][dt]);
        oacc[s][dt] = MFMA_16x16x32(pa[s][1], vb[1][dt], oacc[s][dt]);
      }
    __builtin_amdgcn_s_setprio(0);

    __syncthreads();  // implicit vmcnt(0): stage landed; all waves' reads done
  }

  // ---- epilogue: reduce denominators across lg groups, normalize, store ----
#pragma unroll
  for (int s = 0; s < 2; s++) {
    float v = lr[s];
    v += __shfl_xor(v, 16);
    v += __shfl_xor(v, 32);
#pragma unroll
    for (int r = 0; r < 4; r++) {
      const float inv = 1.0f / __shfl(v, lg * 4 + r);
      const size_t row = (size_t)(b * 1024 + qbase + s * 16 + lg * 4 + r);
#pragma unroll
      for (int dt = 0; dt < 4; dt++)
        ctx[row * 1024 + h * 64 + dt * 16 + l15] = (bf16_t)(oacc[s][dt][r] * inv);
    }
  }
}

extern "C" void kernel_launch(void* const* d_in, const int* in_sizes, int n_in,
                              void* d_out, int out_size, void* d_ws, size_t ws_size,
                              hipStream_t stream) {
  (void)in_sizes; (void)n_in; (void)out_size; (void)ws_size;
  const float* x = (const float*)d_in[0];
  const float* w_qkv = (const float*)d_in[1];
  const float* w_out = (const float*)d_in[2];
  float* out = (float*)d_out;
  char* ws = (char*)d_ws;

  bf16_t* x_b   = (bf16_t*)(ws);                        // 16 MB
  bf16_t* qkv_b = (bf16_t*)(ws + (size_t)(16 << 20));   // 48 MB
  bf16_t* wqT   = (bf16_t*)(ws + (size_t)(64 << 20));   // 6 MB
  bf16_t* woT   = (bf16_t*)(ws + (size_t)(70 << 20));   // 2 MB
  bf16_t* ctx_b = (bf16_t*)(ws + (size_t)(72 << 20));   // 16 MB

  // Q columns pre-scaled by log2(e)/32 so attn softmax is exp2(S) directly.
  const float qsc = 0.045084220027780106f;  // log2(e)/32

  cvt_kernel<<<8388608 / 8 / 256, 256, 0, stream>>>(x, x_b, 8388608 / 8);
  tcvt_kernel<<<dim3(3072 / 32, 1024 / 32), 256, 0, stream>>>(w_qkv, wqT, 1024, 3072);
  tcvt_kernel<<<dim3(1024 / 32, 1024 / 32), 256, 0, stream>>>(w_out, woT, 1024, 1024);

  gemm_bt_kernel<bf16_t><<<dim3(3072 / 128, 8192 / 128), 256, 0, stream>>>(
      x_b, wqT, qkv_b, 8192, 3072, 1024, 1024, qsc);
  attn_kernel<<<1024, 256, 0, stream>>>(qkv_b, ctx_b);
  gemm_bt_kernel<float><<<dim3(1024 / 128, 8192 / 128), 256, 0, stream>>>(
      ctx_b, woT, out, 8192, 1024, 1024, 0, 1.0f);
}

// Round 8
// 177.533 us; speedup vs baseline: 1.1147x; 1.1147x over previous
//
#include <hip/hip_runtime.h>
#include <hip/hip_bf16.h>

typedef __bf16 bf16_t;
typedef __bf16 bf16x8 __attribute__((ext_vector_type(8)));
typedef __bf16 bf16x4 __attribute__((ext_vector_type(4)));
typedef float f32x4 __attribute__((ext_vector_type(4)));

constexpr int LD = 3072;

#define MFMA_16x16x32(a, b, c) __builtin_amdgcn_mfma_f32_16x16x32_bf16((a), (b), (c), 0, 0, 0)

#define GLOAD_LDS16(g, l)                                               \
  __builtin_amdgcn_global_load_lds(                                     \
      (const __attribute__((address_space(1))) void*)(g),               \
      (__attribute__((address_space(3))) void*)(l), 16, 0, 0)

#define TRREAD(dst, addr, imm) \
  asm volatile("ds_read_b64_tr_b16 %0, %1 offset:" imm : "=v"(dst) : "v"(addr))

// ---------------- fp32 -> bf16 convert (16B-store vectorized) ----------------
__global__ void cvt_kernel(const float* __restrict__ in, bf16_t* __restrict__ out, int n8) {
  int i = blockIdx.x * blockDim.x + threadIdx.x;
  if (i >= n8) return;
  const float4 a = reinterpret_cast<const float4*>(in)[2 * i];
  const float4 c = reinterpret_cast<const float4*>(in)[2 * i + 1];
  bf16x8 o;
  o[0] = (bf16_t)a.x; o[1] = (bf16_t)a.y; o[2] = (bf16_t)a.z; o[3] = (bf16_t)a.w;
  o[4] = (bf16_t)c.x; o[5] = (bf16_t)c.y; o[6] = (bf16_t)c.z; o[7] = (bf16_t)c.w;
  reinterpret_cast<bf16x8*>(out)[i] = o;
}

// ------------- transpose + convert: out[c][r] = (bf16) in[r][c] -------------
__global__ void tcvt_kernel(const float* __restrict__ in, bf16_t* __restrict__ out, int R, int C) {
  __shared__ float tile[32][33];
  const int c0 = blockIdx.x * 32, r0 = blockIdx.y * 32;
  const int tx = threadIdx.x & 31, ty = threadIdx.x >> 5;  // 32 x 8
#pragma unroll
  for (int i = 0; i < 32; i += 8)
    tile[ty + i][tx] = in[(size_t)(r0 + ty + i) * C + (c0 + tx)];
  __syncthreads();
#pragma unroll
  for (int i = 0; i < 32; i += 8)
    out[(size_t)(c0 + ty + i) * R + (r0 + tx)] = (bf16_t)tile[tx][ty + i];
}

// ------------- bf16 GEMM: C[M][N] = A[M][K] * Bt[N][K]^T -------------
template <typename OutT>
__global__ __launch_bounds__(256) void gemm_bt_kernel(
    const bf16_t* __restrict__ A, const bf16_t* __restrict__ Bt, OutT* __restrict__ C,
    int M, int N, int K, int q_cols, float q_scale) {
  __shared__ bf16_t As[2][4096];
  __shared__ bf16_t Bs[2][4096];
  const int tid = threadIdx.x;
  const int lane = tid & 63;
  const int wave = tid >> 6;
  const int l15 = lane & 15, lg = lane >> 4;
  const int wr = wave >> 1, wc = wave & 1;
  const int brow = blockIdx.y * 128, bcol = blockIdx.x * 128;

  f32x4 acc[4][4] = {};

  const int srow = tid >> 2;
  const int scol = (tid & 3) * 8;
  const bf16_t* Ag = A + (size_t)(brow + srow) * K + scol;
  const bf16_t* Bg = Bt + (size_t)(bcol + srow) * K + scol;

  {
    bf16_t* aw = &As[0][wave * 512];
    bf16_t* bw = &Bs[0][wave * 512];
    GLOAD_LDS16(Ag, aw);
    GLOAD_LDS16(Ag + (size_t)64 * K, aw + 2048);
    GLOAD_LDS16(Bg, bw);
    GLOAD_LDS16(Bg + (size_t)64 * K, bw + 2048);
  }
  __syncthreads();

  const int nsteps = K >> 5;
  for (int i = 0; i < nsteps; i++) {
    if (i + 1 < nsteps) {
      const int k0 = (i + 1) << 5;
      bf16_t* aw = &As[(i + 1) & 1][wave * 512];
      bf16_t* bw = &Bs[(i + 1) & 1][wave * 512];
      GLOAD_LDS16(Ag + k0, aw);
      GLOAD_LDS16(Ag + k0 + (size_t)64 * K, aw + 2048);
      GLOAD_LDS16(Bg + k0, bw);
      GLOAD_LDS16(Bg + k0 + (size_t)64 * K, bw + 2048);
    }
    const bf16_t* as = As[i & 1];
    const bf16_t* bs = Bs[i & 1];
    bf16x8 af[4], bfr[4];
#pragma unroll
    for (int j = 0; j < 4; j++)
      af[j] = *reinterpret_cast<const bf16x8*>(as + (wr * 64 + j * 16 + l15) * 32 + lg * 8);
#pragma unroll
    for (int j = 0; j < 4; j++)
      bfr[j] = *reinterpret_cast<const bf16x8*>(bs + (wc * 64 + j * 16 + l15) * 32 + lg * 8);
#pragma unroll
    for (int j = 0; j < 4; j++)
#pragma unroll
      for (int k = 0; k < 4; k++)
        acc[j][k] = MFMA_16x16x32(af[j], bfr[k], acc[j][k]);
    __syncthreads();
  }

  const float sc = (bcol < q_cols) ? q_scale : 1.0f;  // block-uniform
#pragma unroll
  for (int i = 0; i < 4; i++)
#pragma unroll
    for (int j = 0; j < 4; j++)
#pragma unroll
      for (int r = 0; r < 4; r++) {
        const size_t row = (size_t)(brow + wr * 64 + i * 16 + lg * 4 + r);
        const size_t col = (size_t)(bcol + wc * 64 + j * 16 + l15);
        C[row * N + col] = (OutT)(acc[i][j][r] * sc);
      }
}

// ------------- fused attention (v8 = v7 + (256,3) cap + split PV) -------------
// K and V staged through LDS once per block. K: XOR chunk swizzle (source-side,
// rule #21). V: pi-subtiled for ds_read_b64_tr_b16. In-register P via swapped
// QK^T. Split PV: ks0 tr-reads issued before softmax (latency hidden under
// exp2), ks1 issued after; consume with lgkmcnt(8) / lgkmcnt(0). Halves the
// live V-fragment set -> fits the (256,3) 170-reg cap without spilling.
__device__ __forceinline__ unsigned pack_bf16_pair(float a, float b) {
  union { __hip_bfloat162 h; unsigned u; } c;
  c.h = __float22bfloat162_rn(float2{a, b});  // v_cvt_pk_bf16_f32
  return c.u;
}

__global__ __launch_bounds__(256, 3) void attn_kernel(const bf16_t* __restrict__ qkv,
                                                      bf16_t* __restrict__ ctx) {
  __shared__ bf16_t Ks[2][4096];  // swizzled K, double-buffered (16 KB)
  __shared__ bf16_t Vs[2][4096];  // pi-subtiled V, double-buffered (16 KB)
  const int tid = threadIdx.x, lane = tid & 63, wave = tid >> 6;
  const int l15 = lane & 15, lg = (lane >> 4) & 3;
  // XCD-aware decode: all 8 q-tiles of one (h,b) on one XCD (K/V L2 reuse)
  const int flat = blockIdx.x;
  const int xcd = flat & 7, rr = flat >> 3;
  const int qt = rr & 7;
  const int hb = xcd * 16 + (rr >> 3);
  const int h = hb & 15, b = hb >> 4;
  const size_t base = (size_t)b * 1024 * LD;
  const int qbase = qt * 128 + wave * 32;

  bf16x8 qa[2][2];
#pragma unroll
  for (int s = 0; s < 2; s++) {
    const bf16_t* qp = qkv + base + (size_t)(qbase + s * 16 + l15) * LD + h * 64 + lg * 8;
    qa[s][0] = *reinterpret_cast<const bf16x8*>(qp);
    qa[s][1] = *reinterpret_cast<const bf16x8*>(qp + 32);
  }

  const bf16_t* Kb = qkv + base + 1024 + h * 64;
  const bf16_t* Vb = qkv + base + 2048 + h * 64;

  // --- K staging source (XOR-swizzled chunks) ---
  const int krr = lane >> 3;
  const int kcc = (lane & 7) ^ krr;
  const bf16_t* ksrc0 = Kb + (size_t)(wave * 16 + krr) * LD + kcc * 8;
  const bf16_t* ksrc1 = ksrc0 + (size_t)8 * LD;

  // --- V staging source (pi layout) ---
  const int vd0 = (lane & 1) * 8 + wave * 16;
  const int vkv = ((lane >> 1) & 3) + ((lane >> 3) & 3) * 4 + (lane >> 5) * 16;
  const bf16_t* vsrc0 = Vb + (size_t)vkv * LD + vd0;  // kv>>5 == 0
  const bf16_t* vsrc1 = vsrc0 + (size_t)32 * LD;      // kv>>5 == 1

  bf16_t* ksb = &Ks[0][0];
  bf16_t* vsb = &Vs[0][0];
  const char* ksr = (const char*)&Ks[0][0];
  const unsigned vs_byte =
      (unsigned)(size_t)(__attribute__((address_space(3))) void*)(&Vs[0][0]);
  const unsigned tr_lane = vs_byte + lane * 8;

  // K fragment read offsets (swizzled): row R = tt*16+l15, R&7 == l15&7
  const int rx7 = l15 & 7;
  const unsigned kb0 = (unsigned)(l15 * 128 + ((lg ^ rx7) << 4));
  const unsigned kb1 = (unsigned)(l15 * 128 + (((4 | lg) ^ rx7) << 4));

  float lr[2] = {0.f, 0.f};
  f32x4 oacc[2][4] = {};

  // prologue: stage tile 0 into buf 0
  GLOAD_LDS16(ksrc0, ksb + wave * 1024);
  GLOAD_LDS16(ksrc1, ksb + wave * 1024 + 512);
  GLOAD_LDS16(vsrc0, vsb + wave * 1024);
  GLOAD_LDS16(vsrc1, vsb + wave * 1024 + 512);
  ksrc0 += (size_t)64 * LD; ksrc1 += (size_t)64 * LD;
  vsrc0 += (size_t)64 * LD; vsrc1 += (size_t)64 * LD;
  __syncthreads();

  for (int t = 0; t < 16; t++) {
    const int cur = t & 1;
    if (t < 15) {  // stage next tile; drained by this iter's end-barrier
      bf16_t* kd = ksb + (cur ^ 1) * 4096 + wave * 1024;
      bf16_t* vd = vsb + (cur ^ 1) * 4096 + wave * 1024;
      GLOAD_LDS16(ksrc0, kd);
      GLOAD_LDS16(ksrc1, kd + 512);
      GLOAD_LDS16(vsrc0, vd);
      GLOAD_LDS16(vsrc1, vd + 512);
      ksrc0 += (size_t)64 * LD; ksrc1 += (size_t)64 * LD;
      vsrc0 += (size_t)64 * LD; vsrc1 += (size_t)64 * LD;
    }

    // ---- S^T = K Q^T : K fragments from swizzled LDS ----
    f32x4 sacc[2][4] = {};
    const char* kt = ksr + cur * 8192;
    __builtin_amdgcn_s_setprio(1);
#pragma unroll
    for (int tt = 0; tt < 4; tt++) {
      const bf16x8 k0 = *reinterpret_cast<const bf16x8*>(kt + tt * 2048 + kb0);
      const bf16x8 k1 = *reinterpret_cast<const bf16x8*>(kt + tt * 2048 + kb1);
      sacc[0][tt] = MFMA_16x16x32(k0, qa[0][0], sacc[0][tt]);
      sacc[0][tt] = MFMA_16x16x32(k1, qa[0][1], sacc[0][tt]);
      sacc[1][tt] = MFMA_16x16x32(k0, qa[1][0], sacc[1][tt]);
      sacc[1][tt] = MFMA_16x16x32(k1, qa[1][1], sacc[1][tt]);
    }
    __builtin_amdgcn_s_setprio(0);

    // ---- issue ks0 tr-reads; latency hides under softmax ----
    const unsigned ta = tr_lane + (unsigned)cur * 8192;
    bf16x4 tl0, th0, tl2, th2, tl4, th4, tl6, th6;
    TRREAD(tl0, ta, "0");    TRREAD(th0, ta, "512");    // ks0 dt0
    TRREAD(tl2, ta, "2048"); TRREAD(th2, ta, "2560");   // ks0 dt1
    TRREAD(tl4, ta, "4096"); TRREAD(th4, ta, "4608");   // ks0 dt2
    TRREAD(tl6, ta, "6144"); TRREAD(th6, ta, "6656");   // ks0 dt3
    __builtin_amdgcn_sched_barrier(0);  // softmax stays below tr-read issue

    // ---- no-max softmax (scale pre-folded into Q at gemm1 epilogue) ----
    unsigned pu[16];
    float ls0 = 0.f, ls1 = 0.f;
#pragma unroll
    for (int tt = 0; tt < 4; tt++) {
      const float a0 = __builtin_exp2f(sacc[0][tt][0]);
      const float a1 = __builtin_exp2f(sacc[0][tt][1]);
      const float a2 = __builtin_exp2f(sacc[0][tt][2]);
      const float a3 = __builtin_exp2f(sacc[0][tt][3]);
      ls0 += (a0 + a1) + (a2 + a3);
      pu[(tt >> 1) * 4 + (tt & 1) * 2 + 0] = pack_bf16_pair(a0, a1);
      pu[(tt >> 1) * 4 + (tt & 1) * 2 + 1] = pack_bf16_pair(a2, a3);
      const float b0 = __builtin_exp2f(sacc[1][tt][0]);
      const float b1 = __builtin_exp2f(sacc[1][tt][1]);
      const float b2 = __builtin_exp2f(sacc[1][tt][2]);
      const float b3 = __builtin_exp2f(sacc[1][tt][3]);
      ls1 += (b0 + b1) + (b2 + b3);
      pu[8 + (tt >> 1) * 4 + (tt & 1) * 2 + 0] = pack_bf16_pair(b0, b1);
      pu[8 + (tt >> 1) * 4 + (tt & 1) * 2 + 1] = pack_bf16_pair(b2, b3);
    }
    lr[0] += ls0;
    lr[1] += ls1;
    bf16x8 pa[2][2];
    pa[0][0] = *reinterpret_cast<bf16x8*>(&pu[0]);
    pa[0][1] = *reinterpret_cast<bf16x8*>(&pu[4]);
    pa[1][0] = *reinterpret_cast<bf16x8*>(&pu[8]);
    pa[1][1] = *reinterpret_cast<bf16x8*>(&pu[12]);

    // ---- issue ks1 tr-reads (outstanding: 8 ks1 after ks0 retires) ----
    bf16x4 tl1, th1, tl3, th3, tl5, th5, tl7, th7;
    TRREAD(tl1, ta, "1024"); TRREAD(th1, ta, "1536");   // ks1 dt0
    TRREAD(tl3, ta, "3072"); TRREAD(th3, ta, "3584");   // ks1 dt1
    TRREAD(tl5, ta, "5120"); TRREAD(th5, ta, "5632");   // ks1 dt2
    TRREAD(tl7, ta, "7168"); TRREAD(th7, ta, "7680");   // ks1 dt3

    // ---- PV half 1 (ks0): wait only the first 8 tr-reads ----
    asm volatile("s_waitcnt lgkmcnt(8)" ::: "memory");
    __builtin_amdgcn_sched_barrier(0);
    {
      bf16x8 vb0[4];
      vb0[0] = __builtin_shufflevector(tl0, th0, 0, 1, 2, 3, 4, 5, 6, 7);
      vb0[1] = __builtin_shufflevector(tl2, th2, 0, 1, 2, 3, 4, 5, 6, 7);
      vb0[2] = __builtin_shufflevector(tl4, th4, 0, 1, 2, 3, 4, 5, 6, 7);
      vb0[3] = __builtin_shufflevector(tl6, th6, 0, 1, 2, 3, 4, 5, 6, 7);
      __builtin_amdgcn_s_setprio(1);
#pragma unroll
      for (int s = 0; s < 2; s++)
#pragma unroll
        for (int dt = 0; dt < 4; dt++)
          oacc[s][dt] = MFMA_16x16x32(pa[s][0], vb0[dt], oacc[s][dt]);
      __builtin_amdgcn_s_setprio(0);
    }

    // ---- PV half 2 (ks1) ----
    asm volatile("s_waitcnt lgkmcnt(0)" ::: "memory");
    __builtin_amdgcn_sched_barrier(0);
    {
      bf16x8 vb1[4];
      vb1[0] = __builtin_shufflevector(tl1, th1, 0, 1, 2, 3, 4, 5, 6, 7);
      vb1[1] = __builtin_shufflevector(tl3, th3, 0, 1, 2, 3, 4, 5, 6, 7);
      vb1[2] = __builtin_shufflevector(tl5, th5, 0, 1, 2, 3, 4, 5, 6, 7);
      vb1[3] = __builtin_shufflevector(tl7, th7, 0, 1, 2, 3, 4, 5, 6, 7);
      __builtin_amdgcn_s_setprio(1);
#pragma unroll
      for (int s = 0; s < 2; s++)
#pragma unroll
        for (int dt = 0; dt < 4; dt++)
          oacc[s][dt] = MFMA_16x16x32(pa[s][1], vb1[dt], oacc[s][dt]);
      __builtin_amdgcn_s_setprio(0);
    }

    __syncthreads();  // implicit vmcnt(0): stage landed; all waves' reads done
  }

  // ---- epilogue: reduce denominators across lg groups, normalize, store ----
#pragma unroll
  for (int s = 0; s < 2; s++) {
    float v = lr[s];
    v += __shfl_xor(v, 16);
    v += __shfl_xor(v, 32);
#pragma unroll
    for (int r = 0; r < 4; r++) {
      const float inv = 1.0f / __shfl(v, lg * 4 + r);
      const size_t row = (size_t)(b * 1024 + qbase + s * 16 + lg * 4 + r);
#pragma unroll
      for (int dt = 0; dt < 4; dt++)
        ctx[row * 1024 + h * 64 + dt * 16 + l15] = (bf16_t)(oacc[s][dt][r] * inv);
    }
  }
}

extern "C" void kernel_launch(void* const* d_in, const int* in_sizes, int n_in,
                              void* d_out, int out_size, void* d_ws, size_t ws_size,
                              hipStream_t stream) {
  (void)in_sizes; (void)n_in; (void)out_size; (void)ws_size;
  const float* x = (const float*)d_in[0];
  const float* w_qkv = (const float*)d_in[1];
  const float* w_out = (const float*)d_in[2];
  float* out = (float*)d_out;
  char* ws = (char*)d_ws;

  bf16_t* x_b   = (bf16_t*)(ws);                        // 16 MB
  bf16_t* qkv_b = (bf16_t*)(ws + (size_t)(16 << 20));   // 48 MB
  bf16_t* wqT   = (bf16_t*)(ws + (size_t)(64 << 20));   // 6 MB
  bf16_t* woT   = (bf16_t*)(ws + (size_t)(70 << 20));   // 2 MB
  bf16_t* ctx_b = (bf16_t*)(ws + (size_t)(72 << 20));   // 16 MB

  // Q columns pre-scaled by log2(e)/32 so attn softmax is exp2(S) directly.
  const float qsc = 0.045084220027780106f;  // log2(e)/32

  cvt_kernel<<<8388608 / 8 / 256, 256, 0, stream>>>(x, x_b, 8388608 / 8);
  tcvt_kernel<<<dim3(3072 / 32, 1024 / 32), 256, 0, stream>>>(w_qkv, wqT, 1024, 3072);
  tcvt_kernel<<<dim3(1024 / 32, 1024 / 32), 256, 0, stream>>>(w_out, woT, 1024, 1024);

  gemm_bt_kernel<bf16_t><<<dim3(3072 / 128, 8192 / 128), 256, 0, stream>>>(
      x_b, wqT, qkv_b, 8192, 3072, 1024, 1024, qsc);
  attn_kernel<<<1024, 256, 0, stream>>>(qkv_b, ctx_b);
  gemm_bt_kernel<float><<<dim3(1024 / 128, 8192 / 128), 256, 0, stream>>>(
      ctx_b, woT, out, 8192, 1024, 1024, 0, 1.0f);
}

// Round 9
// 169.851 us; speedup vs baseline: 1.1651x; 1.0452x over previous
//
#include <hip/hip_runtime.h>
#include <hip/hip_bf16.h>

typedef __bf16 bf16_t;
typedef __bf16 bf16x8 __attribute__((ext_vector_type(8)));
typedef __bf16 bf16x4 __attribute__((ext_vector_type(4)));
typedef float f32x4 __attribute__((ext_vector_type(4)));

constexpr int LD = 3072;

#define MFMA_16x16x32(a, b, c) __builtin_amdgcn_mfma_f32_16x16x32_bf16((a), (b), (c), 0, 0, 0)

#define GLOAD_LDS16(g, l)                                               \
  __builtin_amdgcn_global_load_lds(                                     \
      (const __attribute__((address_space(1))) void*)(g),               \
      (__attribute__((address_space(3))) void*)(l), 16, 0, 0)

#define TRREAD(dst, addr, imm) \
  asm volatile("ds_read_b64_tr_b16 %0, %1 offset:" imm : "=v"(dst) : "v"(addr))

#define BAR __builtin_amdgcn_s_barrier()
#define LGKM0 do { asm volatile("s_waitcnt lgkmcnt(0)" ::: "memory"); \
                   __builtin_amdgcn_sched_barrier(0); } while (0)

// ---------------- fp32 -> bf16 convert (16B-store vectorized) ----------------
__global__ void cvt_kernel(const float* __restrict__ in, bf16_t* __restrict__ out, int n8) {
  int i = blockIdx.x * blockDim.x + threadIdx.x;
  if (i >= n8) return;
  const float4 a = reinterpret_cast<const float4*>(in)[2 * i];
  const float4 c = reinterpret_cast<const float4*>(in)[2 * i + 1];
  bf16x8 o;
  o[0] = (bf16_t)a.x; o[1] = (bf16_t)a.y; o[2] = (bf16_t)a.z; o[3] = (bf16_t)a.w;
  o[4] = (bf16_t)c.x; o[5] = (bf16_t)c.y; o[6] = (bf16_t)c.z; o[7] = (bf16_t)c.w;
  reinterpret_cast<bf16x8*>(out)[i] = o;
}

// ------------- transpose + convert: out[c][r] = (bf16) in[r][c] -------------
__global__ void tcvt_kernel(const float* __restrict__ in, bf16_t* __restrict__ out, int R, int C) {
  __shared__ float tile[32][33];
  const int c0 = blockIdx.x * 32, r0 = blockIdx.y * 32;
  const int tx = threadIdx.x & 31, ty = threadIdx.x >> 5;  // 32 x 8
#pragma unroll
  for (int i = 0; i < 32; i += 8)
    tile[ty + i][tx] = in[(size_t)(r0 + ty + i) * C + (c0 + tx)];
  __syncthreads();
#pragma unroll
  for (int i = 0; i < 32; i += 8)
    out[(size_t)(c0 + ty + i) * R + (r0 + tx)] = (bf16_t)tile[tx][ty + i];
}

// ------------- GEMM1 (QKV): 256x256 tile, 8-phase, counted vmcnt -------------
// A[8192][1024] bf16, Bt[3072][1024] bf16, C[8192][3072] bf16.
// 512 thr = 8 waves (2M x 4N), per-wave 128x64 out (8x4 16x16 frags).
// BK=64, double-buffered; LDS [2buf][2half][128][64] per matrix = 128 KB dyn.
// XOR chunk-swizzle (chunk^=row&7) pre-applied on global src; reads use same.
// Stage slots (half-tile = 2 gload_lds/thread): ph1:Ah1(2i+1) ph2:Bh0(2i+1)
// ph3:Bh1(2i+1) ph4:Ah0(2i+2) ph5:Ah1(2i+2) ph6:Bh0(2i+2) ph7:Bh1(2i+2)
// ph8:Ah0(2i+3). WAR: A-halves of a tile last-read at its 3rd phase, B at its
// 4th; every slot issues >=1 barrier later. RAW: vmcnt(2) at ph4/ph8 drains
// all but the current phase's 2 loads -> next tile's 4 halves landed.
__global__ __launch_bounds__(512, 2) void gemm_qkv_256(
    const bf16_t* __restrict__ A, const bf16_t* __restrict__ Bt,
    bf16_t* __restrict__ C, float q_scale) {
  constexpr int K = 1024;
  extern __shared__ char smem[];
  char* asB = smem;           // 64 KB: A [2][2][128][64]
  char* bsB = smem + 65536;   // 64 KB: B

  const int t = threadIdx.x;
  const int lane = t & 63, wave = t >> 6;
  const int l15 = lane & 15, lg = lane >> 4;
  const int wr = wave >> 2, wc = wave & 3;

  // XCD-chunked bijective swizzle (384 = 8 XCD x 48)
  const int bid = blockIdx.x;
  const int wg = (bid & 7) * 48 + (bid >> 3);
  const int brow = (wg & 31) * 256;
  const int bcol = (wg >> 5) * 256;

  // staging source (pre-swizzled chunk): thread t covers row t>>3, chunk t&7
  const int srow = t >> 3;
  const int schk = (t & 7) ^ (srow & 7);
  const bf16_t* aS = A + (size_t)(brow + srow) * K + schk * 8;
  const bf16_t* bS = Bt + (size_t)(bcol + srow) * K + schk * 8;
  const int ldst = t * 8;  // elems into an 8KB round

#define STG_A(T, H) do {                                                      \
    const bf16_t* _s = aS + (size_t)((H) * 128) * K + (T) * 64;               \
    bf16_t* _d = (bf16_t*)(asB + ((T) & 1) * 32768 + (H) * 16384) + ldst;     \
    GLOAD_LDS16(_s, _d);                                                      \
    GLOAD_LDS16(_s + (size_t)64 * K, _d + 4096);                              \
  } while (0)
#define STG_B(T, H) do {                                                      \
    const bf16_t* _s = bS + (size_t)((H) * 128) * K + (T) * 64;               \
    bf16_t* _d = (bf16_t*)(bsB + ((T) & 1) * 32768 + (H) * 16384) + ldst;     \
    GLOAD_LDS16(_s, _d);                                                      \
    GLOAD_LDS16(_s + (size_t)64 * K, _d + 4096);                              \
  } while (0)

  // fragment read bases (bytes); swizzled chunks c0 (ks0), c1 (ks1)
  const int rx = l15 & 7;
  const unsigned c0 = ((unsigned)(lg ^ rx)) << 4;
  const unsigned c1 = ((unsigned)((4 | lg) ^ rx)) << 4;
  const unsigned a_rd = (unsigned)(wr * 16384 + l15 * 128);
  const unsigned b_rd = (unsigned)((wc >> 1) * 16384 + (wc & 1) * 8192 + l15 * 128);

  f32x4 acc[8][4] = {};
  bf16x8 af[4][2], bfr[2][2];

#define RD_AF(BUF, MH) do { _Pragma("unroll")                                 \
    for (int m = 0; m < 4; ++m) {                                             \
      const char* _p = asB + (BUF) * 32768 + a_rd + ((MH) * 4 + m) * 2048;    \
      af[m][0] = *(const bf16x8*)(_p + c0);                                   \
      af[m][1] = *(const bf16x8*)(_p + c1); } } while (0)
#define RD_BF(BUF, NH) do { _Pragma("unroll")                                 \
    for (int n = 0; n < 2; ++n) {                                             \
      const char* _p = bsB + (BUF) * 32768 + b_rd + ((NH) * 2 + n) * 2048;    \
      bfr[n][0] = *(const bf16x8*)(_p + c0);                                  \
      bfr[n][1] = *(const bf16x8*)(_p + c1); } } while (0)
#define MM16(MH, NH) do {                                                     \
    __builtin_amdgcn_s_setprio(1);                                            \
    _Pragma("unroll")                                                         \
    for (int m = 0; m < 4; ++m) { _Pragma("unroll")                           \
      for (int n = 0; n < 2; ++n) {                                           \
        acc[(MH)*4+m][(NH)*2+n] =                                             \
            MFMA_16x16x32(af[m][0], bfr[n][0], acc[(MH)*4+m][(NH)*2+n]);      \
        acc[(MH)*4+m][(NH)*2+n] =                                             \
            MFMA_16x16x32(af[m][1], bfr[n][1], acc[(MH)*4+m][(NH)*2+n]); } }  \
    __builtin_amdgcn_s_setprio(0); } while (0)

  // prologue: tile0 full + Ah0(1); keep Ah0(1)'s 2 loads in flight
  STG_A(0, 0); STG_A(0, 1); STG_B(0, 0); STG_B(0, 1); STG_A(1, 0);
  asm volatile("s_waitcnt vmcnt(2)" ::: "memory");
  BAR;

  for (int i = 0; i < 8; ++i) {
    const int T1 = 2 * i + 1, T2 = 2 * i + 2, T3 = 2 * i + 3;
    const bool pf = (i < 7);
    // ---- ph1: tile 2i (buf0) quad (0,0) ----
    STG_A(T1, 1);
    RD_AF(0, 0); RD_BF(0, 0);
    BAR; LGKM0; MM16(0, 0); BAR;
    // ---- ph2: (0,1) ----
    STG_B(T1, 0);
    RD_BF(0, 1);
    BAR; LGKM0; MM16(0, 1); BAR;
    // ---- ph3: (1,1) ----
    STG_B(T1, 1);
    RD_AF(0, 1);
    BAR; LGKM0; MM16(1, 1); BAR;
    // ---- ph4: (1,0); drain tile 2i+1's stages ----
    if (pf) STG_A(T2, 0);
    RD_BF(0, 0);
    BAR; LGKM0; MM16(1, 0);
    if (pf) asm volatile("s_waitcnt vmcnt(2)" ::: "memory");
    else    asm volatile("s_waitcnt vmcnt(0)" ::: "memory");
    BAR;
    // ---- ph5: tile 2i+1 (buf1) quad (0,0) ----
    if (pf) STG_A(T2, 1);
    RD_AF(1, 0); RD_BF(1, 0);
    BAR; LGKM0; MM16(0, 0); BAR;
    // ---- ph6: (0,1) ----
    if (pf) STG_B(T2, 0);
    RD_BF(1, 1);
    BAR; LGKM0; MM16(0, 1); BAR;
    // ---- ph7: (1,1) ----
    if (pf) STG_B(T2, 1);
    RD_AF(1, 1);
    BAR; LGKM0; MM16(1, 1); BAR;
    // ---- ph8: (1,0); drain tile 2i+2's stages ----
    if (pf) STG_A(T3, 0);
    RD_BF(1, 0);
    BAR; LGKM0; MM16(1, 0);
    asm volatile("s_waitcnt vmcnt(2)" ::: "memory");
    BAR;
  }

  // ---- epilogue: C write (bf16) with q-scale on cols < 1024 ----
  const float sc = (bcol < 1024) ? q_scale : 1.0f;
  const int crow0 = brow + wr * 128 + lg * 4;
  const int ccol0 = bcol + wc * 64 + l15;
#pragma unroll
  for (int m = 0; m < 8; ++m)
#pragma unroll
    for (int n = 0; n < 4; ++n)
#pragma unroll
      for (int r = 0; r < 4; ++r)
        C[(size_t)(crow0 + m * 16 + r) * 3072 + ccol0 + n * 16] =
            (bf16_t)(acc[m][n][r] * sc);
#undef STG_A
#undef STG_B
#undef RD_AF
#undef RD_BF
#undef MM16
}

// ------------- bf16 GEMM (128²): C[M][N] = A[M][K] * Bt[N][K]^T -------------
template <typename OutT>
__global__ __launch_bounds__(256) void gemm_bt_kernel(
    const bf16_t* __restrict__ A, const bf16_t* __restrict__ Bt, OutT* __restrict__ C,
    int M, int N, int K, int q_cols, float q_scale) {
  __shared__ bf16_t As[2][4096];
  __shared__ bf16_t Bs[2][4096];
  const int tid = threadIdx.x;
  const int lane = tid & 63;
  const int wave = tid >> 6;
  const int l15 = lane & 15, lg = lane >> 4;
  const int wr = wave >> 1, wc = wave & 1;
  const int brow = blockIdx.y * 128, bcol = blockIdx.x * 128;

  f32x4 acc[4][4] = {};

  const int srow = tid >> 2;
  const int scol = (tid & 3) * 8;
  const bf16_t* Ag = A + (size_t)(brow + srow) * K + scol;
  const bf16_t* Bg = Bt + (size_t)(bcol + srow) * K + scol;

  {
    bf16_t* aw = &As[0][wave * 512];
    bf16_t* bw = &Bs[0][wave * 512];
    GLOAD_LDS16(Ag, aw);
    GLOAD_LDS16(Ag + (size_t)64 * K, aw + 2048);
    GLOAD_LDS16(Bg, bw);
    GLOAD_LDS16(Bg + (size_t)64 * K, bw + 2048);
  }
  __syncthreads();

  const int nsteps = K >> 5;
  for (int i = 0; i < nsteps; i++) {
    if (i + 1 < nsteps) {
      const int k0 = (i + 1) << 5;
      bf16_t* aw = &As[(i + 1) & 1][wave * 512];
      bf16_t* bw = &Bs[(i + 1) & 1][wave * 512];
      GLOAD_LDS16(Ag + k0, aw);
      GLOAD_LDS16(Ag + k0 + (size_t)64 * K, aw + 2048);
      GLOAD_LDS16(Bg + k0, bw);
      GLOAD_LDS16(Bg + k0 + (size_t)64 * K, bw + 2048);
    }
    const bf16_t* as = As[i & 1];
    const bf16_t* bs = Bs[i & 1];
    bf16x8 af[4], bfr[4];
#pragma unroll
    for (int j = 0; j < 4; j++)
      af[j] = *reinterpret_cast<const bf16x8*>(as + (wr * 64 + j * 16 + l15) * 32 + lg * 8);
#pragma unroll
    for (int j = 0; j < 4; j++)
      bfr[j] = *reinterpret_cast<const bf16x8*>(bs + (wc * 64 + j * 16 + l15) * 32 + lg * 8);
#pragma unroll
    for (int j = 0; j < 4; j++)
#pragma unroll
      for (int k = 0; k < 4; k++)
        acc[j][k] = MFMA_16x16x32(af[j], bfr[k], acc[j][k]);
    __syncthreads();
  }

  const float sc = (bcol < q_cols) ? q_scale : 1.0f;  // block-uniform
#pragma unroll
  for (int i = 0; i < 4; i++)
#pragma unroll
    for (int j = 0; j < 4; j++)
#pragma unroll
      for (int r = 0; r < 4; r++) {
        const size_t row = (size_t)(brow + wr * 64 + i * 16 + lg * 4 + r);
        const size_t col = (size_t)(bcol + wc * 64 + j * 16 + l15);
        C[row * N + col] = (OutT)(acc[i][j][r] * sc);
      }
}

// ------------- fused attention (v8, unchanged from R8) -------------
__device__ __forceinline__ unsigned pack_bf16_pair(float a, float b) {
  union { __hip_bfloat162 h; unsigned u; } c;
  c.h = __float22bfloat162_rn(float2{a, b});  // v_cvt_pk_bf16_f32
  return c.u;
}

__global__ __launch_bounds__(256, 3) void attn_kernel(const bf16_t* __restrict__ qkv,
                                                      bf16_t* __restrict__ ctx) {
  __shared__ bf16_t Ks[2][4096];  // swizzled K, double-buffered (16 KB)
  __shared__ bf16_t Vs[2][4096];  // pi-subtiled V, double-buffered (16 KB)
  const int tid = threadIdx.x, lane = tid & 63, wave = tid >> 6;
  const int l15 = lane & 15, lg = (lane >> 4) & 3;
  const int flat = blockIdx.x;
  const int xcd = flat & 7, rr = flat >> 3;
  const int qt = rr & 7;
  const int hb = xcd * 16 + (rr >> 3);
  const int h = hb & 15, b = hb >> 4;
  const size_t base = (size_t)b * 1024 * LD;
  const int qbase = qt * 128 + wave * 32;

  bf16x8 qa[2][2];
#pragma unroll
  for (int s = 0; s < 2; s++) {
    const bf16_t* qp = qkv + base + (size_t)(qbase + s * 16 + l15) * LD + h * 64 + lg * 8;
    qa[s][0] = *reinterpret_cast<const bf16x8*>(qp);
    qa[s][1] = *reinterpret_cast<const bf16x8*>(qp + 32);
  }

  const bf16_t* Kb = qkv + base + 1024 + h * 64;
  const bf16_t* Vb = qkv + base + 2048 + h * 64;

  const int krr = lane >> 3;
  const int kcc = (lane & 7) ^ krr;
  const bf16_t* ksrc0 = Kb + (size_t)(wave * 16 + krr) * LD + kcc * 8;
  const bf16_t* ksrc1 = ksrc0 + (size_t)8 * LD;

  const int vd0 = (lane & 1) * 8 + wave * 16;
  const int vkv = ((lane >> 1) & 3) + ((lane >> 3) & 3) * 4 + (lane >> 5) * 16;
  const bf16_t* vsrc0 = Vb + (size_t)vkv * LD + vd0;
  const bf16_t* vsrc1 = vsrc0 + (size_t)32 * LD;

  bf16_t* ksb = &Ks[0][0];
  bf16_t* vsb = &Vs[0][0];
  const char* ksr = (const char*)&Ks[0][0];
  const unsigned vs_byte =
      (unsigned)(size_t)(__attribute__((address_space(3))) void*)(&Vs[0][0]);
  const unsigned tr_lane = vs_byte + lane * 8;

  const int rx7 = l15 & 7;
  const unsigned kb0 = (unsigned)(l15 * 128 + ((lg ^ rx7) << 4));
  const unsigned kb1 = (unsigned)(l15 * 128 + (((4 | lg) ^ rx7) << 4));

  float lr[2] = {0.f, 0.f};
  f32x4 oacc[2][4] = {};

  GLOAD_LDS16(ksrc0, ksb + wave * 1024);
  GLOAD_LDS16(ksrc1, ksb + wave * 1024 + 512);
  GLOAD_LDS16(vsrc0, vsb + wave * 1024);
  GLOAD_LDS16(vsrc1, vsb + wave * 1024 + 512);
  ksrc0 += (size_t)64 * LD; ksrc1 += (size_t)64 * LD;
  vsrc0 += (size_t)64 * LD; vsrc1 += (size_t)64 * LD;
  __syncthreads();

  for (int t = 0; t < 16; t++) {
    const int cur = t & 1;
    if (t < 15) {
      bf16_t* kd = ksb + (cur ^ 1) * 4096 + wave * 1024;
      bf16_t* vd = vsb + (cur ^ 1) * 4096 + wave * 1024;
      GLOAD_LDS16(ksrc0, kd);
      GLOAD_LDS16(ksrc1, kd + 512);
      GLOAD_LDS16(vsrc0, vd);
      GLOAD_LDS16(vsrc1, vd + 512);
      ksrc0 += (size_t)64 * LD; ksrc1 += (size_t)64 * LD;
      vsrc0 += (size_t)64 * LD; vsrc1 += (size_t)64 * LD;
    }

    f32x4 sacc[2][4] = {};
    const char* kt = ksr + cur * 8192;
    __builtin_amdgcn_s_setprio(1);
#pragma unroll
    for (int tt = 0; tt < 4; tt++) {
      const bf16x8 k0 = *reinterpret_cast<const bf16x8*>(kt + tt * 2048 + kb0);
      const bf16x8 k1 = *reinterpret_cast<const bf16x8*>(kt + tt * 2048 + kb1);
      sacc[0][tt] = MFMA_16x16x32(k0, qa[0][0], sacc[0][tt]);
      sacc[0][tt] = MFMA_16x16x32(k1, qa[0][1], sacc[0][tt]);
      sacc[1][tt] = MFMA_16x16x32(k0, qa[1][0], sacc[1][tt]);
      sacc[1][tt] = MFMA_16x16x32(k1, qa[1][1], sacc[1][tt]);
    }
    __builtin_amdgcn_s_setprio(0);

    const unsigned ta = tr_lane + (unsigned)cur * 8192;
    bf16x4 tl0, th0, tl2, th2, tl4, th4, tl6, th6;
    TRREAD(tl0, ta, "0");    TRREAD(th0, ta, "512");
    TRREAD(tl2, ta, "2048"); TRREAD(th2, ta, "2560");
    TRREAD(tl4, ta, "4096"); TRREAD(th4, ta, "4608");
    TRREAD(tl6, ta, "6144"); TRREAD(th6, ta, "6656");
    __builtin_amdgcn_sched_barrier(0);

    unsigned pu[16];
    float ls0 = 0.f, ls1 = 0.f;
#pragma unroll
    for (int tt = 0; tt < 4; tt++) {
      const float a0 = __builtin_exp2f(sacc[0][tt][0]);
      const float a1 = __builtin_exp2f(sacc[0][tt][1]);
      const float a2 = __builtin_exp2f(sacc[0][tt][2]);
      const float a3 = __builtin_exp2f(sacc[0][tt][3]);
      ls0 += (a0 + a1) + (a2 + a3);
      pu[(tt >> 1) * 4 + (tt & 1) * 2 + 0] = pack_bf16_pair(a0, a1);
      pu[(tt >> 1) * 4 + (tt & 1) * 2 + 1] = pack_bf16_pair(a2, a3);
      const float b0 = __builtin_exp2f(sacc[1][tt][0]);
      const float b1 = __builtin_exp2f(sacc[1][tt][1]);
      const float b2 = __builtin_exp2f(sacc[1][tt][2]);
      const float b3 = __builtin_exp2f(sacc[1][tt][3]);
      ls1 += (b0 + b1) + (b2 + b3);
      pu[8 + (tt >> 1) * 4 + (tt & 1) * 2 + 0] = pack_bf16_pair(b0, b1);
      pu[8 + (tt >> 1) * 4 + (tt & 1) * 2 + 1] = pack_bf16_pair(b2, b3);
    }
    lr[0] += ls0;
    lr[1] += ls1;
    bf16x8 pa[2][2];
    pa[0][0] = *reinterpret_cast<bf16x8*>(&pu[0]);
    pa[0][1] = *reinterpret_cast<bf16x8*>(&pu[4]);
    pa[1][0] = *reinterpret_cast<bf16x8*>(&pu[8]);
    pa[1][1] = *reinterpret_cast<bf16x8*>(&pu[12]);

    bf16x4 tl1, th1, tl3, th3, tl5, th5, tl7, th7;
    TRREAD(tl1, ta, "1024"); TRREAD(th1, ta, "1536");
    TRREAD(tl3, ta, "3072"); TRREAD(th3, ta, "3584");
    TRREAD(tl5, ta, "5120"); TRREAD(th5, ta, "5632");
    TRREAD(tl7, ta, "7168"); TRREAD(th7, ta, "7680");

    asm volatile("s_waitcnt lgkmcnt(8)" ::: "memory");
    __builtin_amdgcn_sched_barrier(0);
    {
      bf16x8 vb0[4];
      vb0[0] = __builtin_shufflevector(tl0, th0, 0, 1, 2, 3, 4, 5, 6, 7);
      vb0[1] = __builtin_shufflevector(tl2, th2, 0, 1, 2, 3, 4, 5, 6, 7);
      vb0[2] = __builtin_shufflevector(tl4, th4, 0, 1, 2, 3, 4, 5, 6, 7);
      vb0[3] = __builtin_shufflevector(tl6, th6, 0, 1, 2, 3, 4, 5, 6, 7);
      __builtin_amdgcn_s_setprio(1);
#pragma unroll
      for (int s = 0; s < 2; s++)
#pragma unroll
        for (int dt = 0; dt < 4; dt++)
          oacc[s][dt] = MFMA_16x16x32(pa[s][0], vb0[dt], oacc[s][dt]);
      __builtin_amdgcn_s_setprio(0);
    }

    asm volatile("s_waitcnt lgkmcnt(0)" ::: "memory");
    __builtin_amdgcn_sched_barrier(0);
    {
      bf16x8 vb1[4];
      vb1[0] = __builtin_shufflevector(tl1, th1, 0, 1, 2, 3, 4, 5, 6, 7);
      vb1[1] = __builtin_shufflevector(tl3, th3, 0, 1, 2, 3, 4, 5, 6, 7);
      vb1[2] = __builtin_shufflevector(tl5, th5, 0, 1, 2, 3, 4, 5, 6, 7);
      vb1[3] = __builtin_shufflevector(tl7, th7, 0, 1, 2, 3, 4, 5, 6, 7);
      __builtin_amdgcn_s_setprio(1);
#pragma unroll
      for (int s = 0; s < 2; s++)
#pragma unroll
        for (int dt = 0; dt < 4; dt++)
          oacc[s][dt] = MFMA_16x16x32(pa[s][1], vb1[dt], oacc[s][dt]);
      __builtin_amdgcn_s_setprio(0);
    }

    __syncthreads();
  }

#pragma unroll
  for (int s = 0; s < 2; s++) {
    float v = lr[s];
    v += __shfl_xor(v, 16);
    v += __shfl_xor(v, 32);
#pragma unroll
    for (int r = 0; r < 4; r++) {
      const float inv = 1.0f / __shfl(v, lg * 4 + r);
      const size_t row = (size_t)(b * 1024 + qbase + s * 16 + lg * 4 + r);
#pragma unroll
      for (int dt = 0; dt < 4; dt++)
        ctx[row * 1024 + h * 64 + dt * 16 + l15] = (bf16_t)(oacc[s][dt][r] * inv);
    }
  }
}

extern "C" void kernel_launch(void* const* d_in, const int* in_sizes, int n_in,
                              void* d_out, int out_size, void* d_ws, size_t ws_size,
                              hipStream_t stream) {
  (void)in_sizes; (void)n_in; (void)out_size; (void)ws_size;
  const float* x = (const float*)d_in[0];
  const float* w_qkv = (const float*)d_in[1];
  const float* w_out = (const float*)d_in[2];
  float* out = (float*)d_out;
  char* ws = (char*)d_ws;

  bf16_t* x_b   = (bf16_t*)(ws);                        // 16 MB
  bf16_t* qkv_b = (bf16_t*)(ws + (size_t)(16 << 20));   // 48 MB
  bf16_t* wqT   = (bf16_t*)(ws + (size_t)(64 << 20));   // 6 MB
  bf16_t* woT   = (bf16_t*)(ws + (size_t)(70 << 20));   // 2 MB
  bf16_t* ctx_b = (bf16_t*)(ws + (size_t)(72 << 20));   // 16 MB

  // Q columns pre-scaled by log2(e)/32 so attn softmax is exp2(S) directly.
  const float qsc = 0.045084220027780106f;  // log2(e)/32

  cvt_kernel<<<8388608 / 8 / 256, 256, 0, stream>>>(x, x_b, 8388608 / 8);
  tcvt_kernel<<<dim3(3072 / 32, 1024 / 32), 256, 0, stream>>>(w_qkv, wqT, 1024, 3072);
  tcvt_kernel<<<dim3(1024 / 32, 1024 / 32), 256, 0, stream>>>(w_out, woT, 1024, 1024);

  gemm_qkv_256<<<384, 512, 131072, stream>>>(x_b, wqT, qkv_b, qsc);
  attn_kernel<<<1024, 256, 0, stream>>>(qkv_b, ctx_b);
  gemm_bt_kernel<float><<<dim3(1024 / 128, 8192 / 128), 256, 0, stream>>>(
      ctx_b, woT, out, 8192, 1024, 1024, 0, 1.0f);
}